// Round 3
// baseline (264.506 us; speedup 1.0000x reference)
//
#include <hip/hip_runtime.h>

// ---- types -----------------------------------------------------------------
typedef __bf16 bf16;
typedef __attribute__((ext_vector_type(8))) __bf16 bf16x8;
typedef __attribute__((ext_vector_type(4))) __bf16 bf16x4;
typedef __attribute__((ext_vector_type(4))) float  f32x4;

static __device__ __forceinline__ f32x4 mfma16(bf16x8 a, bf16x8 b, f32x4 c) {
  return __builtin_amdgcn_mfma_f32_16x16x32_bf16(a, b, c, 0, 0, 0);
}
static __device__ __forceinline__ float fexp2(float x) {
  return __builtin_amdgcn_exp2f(x);
}

// exp(s/sqrt(128)) = exp2(s * C1)
#define EXP_C1 (1.4426950408889634f / 11.313708498984760f)

// Granule-major tile format (128 rows x 128 cols bf16, 32KB):
//   elem_off(r,c) = (c>>3)*1024 + r*8 + (c&7)
// MFMA A/B fragment (16 rows x 8 consecutive cols) = contiguous 16B at 16B
// row stride -> fragments load DIRECTLY from global (L2/L3-served), no LDS.

// ============================================================================
// Kernel 0: prep. W[3][128][256] fp32 -> Wc[3][32 g][128 n][8] bf16.
// ============================================================================
__global__ __launch_bounds__(256) void k_prep(
    const float* __restrict__ Wq, const float* __restrict__ Wk,
    const float* __restrict__ Wv, bf16* __restrict__ Wc)
{
  int id = blockIdx.x * 256 + threadIdx.x;      // 48 blocks = 12288 = 3*4096
  int proj = id >> 12, r = id & 4095;
  int g = r >> 7, n = r & 127;
  const float* W = proj == 0 ? Wq : proj == 1 ? Wk : Wv;
  const float4* src = (const float4*)(W + n * 256 + g * 8);
  float4 a = src[0], b = src[1];
  bf16x8 o = { (bf16)a.x, (bf16)a.y, (bf16)a.z, (bf16)a.w,
               (bf16)b.x, (bf16)b.y, (bf16)b.z, (bf16)b.w };
  *(bf16x8*)(Wc + (size_t)proj * 32768 + g * 1024 + n * 8) = o;
}

// ============================================================================
// Kernel 1: QKV projection. grid(3, 512), block 256, NO LDS, no barriers.
// A-fragments: direct global fp32 q + in-reg cvt. B-fragments: Wc bf16 (L2).
// Out 128x128 per block. Q,K granule-major [s][d]; V transposed [d][s].
// ============================================================================
__global__ __launch_bounds__(256, 3) void k_qkv(
    const float* __restrict__ q, const bf16* __restrict__ Wc,
    const float* __restrict__ bq, const float* __restrict__ bk, const float* __restrict__ bv,
    bf16* __restrict__ Qb, bf16* __restrict__ Kb, bf16* __restrict__ VT)
{
  const int bx = blockIdx.x;                    // projection
  const int m0 = blockIdx.y * 128;
  const bf16* W = Wc + (size_t)bx * 32768;
  const float* bias = bx == 0 ? bq : bx == 1 ? bk : bv;

  const int tid = threadIdx.x, lane = tid & 63, wave = tid >> 6;
  const int ln = lane & 15, quad = lane >> 4;
  const int wr = wave >> 1, wc = wave & 1;      // 2x2 waves, 64x64 each

  const float* arow[4];
  for (int i = 0; i < 4; ++i)
    arow[i] = q + (size_t)(m0 + wr * 64 + i * 16 + ln) * 256;

  f32x4 acc[4][4] = {};
  for (int kb = 0; kb < 256; kb += 32) {
    bf16x8 af[4], bfr[4];
    for (int i = 0; i < 4; ++i) {
      const float4* p = (const float4*)(arow[i] + kb + quad * 8);
      float4 x = p[0], y = p[1];
      af[i] = bf16x8{ (bf16)x.x, (bf16)x.y, (bf16)x.z, (bf16)x.w,
                      (bf16)y.x, (bf16)y.y, (bf16)y.z, (bf16)y.w };
    }
    for (int j = 0; j < 4; ++j)
      bfr[j] = *(const bf16x8*)(W + (kb / 8 + quad) * 1024 + (wc * 64 + j * 16 + ln) * 8);
    for (int i = 0; i < 4; ++i)
      for (int j = 0; j < 4; ++j)
        acc[i][j] = mfma16(af[i], bfr[j], acc[i][j]);
  }

  const int b = m0 >> 10, st = (m0 & 1023) >> 7;
  const size_t tbase = ((size_t)b * 8 + st) * 16384;
  if (bx < 2) {                                 // Q,K: granule-major rows=s
    bf16* dst = (bx == 0 ? Qb : Kb) + tbase;
    for (int j = 0; j < 4; ++j) {
      int d = wc * 64 + j * 16 + ln;
      float bb = bias[d];
      size_t gcol = (size_t)(d >> 3) * 1024 + (d & 7);
      for (int i = 0; i < 4; ++i) {
        int rbase = wr * 64 + i * 16 + quad * 4;
        for (int rr = 0; rr < 4; ++rr)
          dst[gcol + (size_t)(rbase + rr) * 8] = (bf16)(acc[i][j][rr] + bb);
      }
    }
  } else {                                      // V: granule-major rows=d (V^T)
    bf16* dst = VT + tbase;
    for (int j = 0; j < 4; ++j) {
      int d = wc * 64 + j * 16 + ln;
      float bb = bias[d];
      for (int i = 0; i < 4; ++i) {
        int s = wr * 64 + i * 16 + quad * 4;
        bf16x4 o = { (bf16)(acc[i][j][0] + bb), (bf16)(acc[i][j][1] + bb),
                     (bf16)(acc[i][j][2] + bb), (bf16)(acc[i][j][3] + bb) };
        *(bf16x4*)&dst[(size_t)(s >> 3) * 1024 + (size_t)d * 8 + (s & 7)] = o;
      }
    }
  }
}

// ============================================================================
// Kernel 2: column stats only. grid(16 kt, 64 b), block 256.
//   inv[b][k] = 1 / sum_q exp2(S[q][k]*C1) for 64 k-columns per block.
//   K-fragments register-resident; Q-fragments streamed from global.
//   Each wave covers a q-quarter (256 rows). No main-loop barriers.
// ============================================================================
__global__ __launch_bounds__(256, 4) void k_stats(
    const bf16* __restrict__ Qb, const bf16* __restrict__ Kb, float* __restrict__ inv)
{
  __shared__ float red[4][64];
  const int kt = blockIdx.x, b = blockIdx.y;
  const int tid = threadIdx.x, lane = tid & 63, wave = tid >> 6;
  const int ln = lane & 15, quad = lane >> 4;

  const bf16* ktile = Kb + ((size_t)b * 8 + (kt >> 1)) * 16384;
  const int krow = (kt & 1) * 64;

  bf16x8 bk_[4][4];                             // [j: 16-k group][kk: d-granule4]
  for (int j = 0; j < 4; ++j)
    for (int kk = 0; kk < 4; ++kk)
      bk_[j][kk] = *(const bf16x8*)(ktile + (kk * 4 + quad) * 1024 + (krow + j * 16 + ln) * 8);

  float cs[4] = {0.f, 0.f, 0.f, 0.f};
  for (int it = 0; it < 16; ++it) {             // 16 rows of q per iter
    int qb = wave * 256 + it * 16;
    const bf16* qt_ = Qb + ((size_t)b * 8 + (qb >> 7)) * 16384;
    int q_local = qb & 127;
    f32x4 acc[4] = {};
    for (int kk = 0; kk < 4; ++kk) {
      bf16x8 a = *(const bf16x8*)(qt_ + (kk * 4 + quad) * 1024 + (q_local + ln) * 8);
      for (int j = 0; j < 4; ++j)
        acc[j] = mfma16(a, bk_[j][kk], acc[j]);
    }
    for (int j = 0; j < 4; ++j)
      for (int rr = 0; rr < 4; ++rr)
        cs[j] += fexp2(acc[j][rr] * EXP_C1);
  }
  for (int j = 0; j < 4; ++j) {                 // reduce over quads (16 q rows)
    cs[j] += __shfl_xor(cs[j], 16, 64);
    cs[j] += __shfl_xor(cs[j], 32, 64);
  }
  if (lane < 16)
    for (int j = 0; j < 4; ++j)
      red[wave][j * 16 + lane] = cs[j];
  __syncthreads();
  if (tid < 64) {
    float s = red[0][tid] + red[1][tid] + red[2][tid] + red[3][tid];
    inv[(size_t)b * 1024 + kt * 64 + tid] = 1.0f / s;
  }
}

// ============================================================================
// Kernel 3: fused S^T = K Q^T -> p = exp*inv -> O += P Vc -> q-max.
// grid(16 qt, 64 b), block 256 (4 waves: w0 = k/d half, w1 = q half).
// S^T orientation puts k in the C-frag REG index -> packed bf16x4 P-stores.
// LDS: Pl 8KB + invl 4KB + redm 1KB -> 4 blocks/CU (VGPR-capped).
// K/V fragments direct from global (L2); Q fragments register-resident.
// ============================================================================
__global__ __launch_bounds__(256, 4) void k_attn(
    const bf16* __restrict__ Qb, const bf16* __restrict__ Kb, const bf16* __restrict__ VT,
    const float* __restrict__ inv, float* __restrict__ Opart)
{
  __shared__ bf16  Pl[4096];                    // [8 kg][64 q][8]
  __shared__ float invl[1024];
  __shared__ float redm[256];

  const int qt = blockIdx.x, b = blockIdx.y;
  const int tid = threadIdx.x, lane = tid & 63, wave = tid >> 6;
  const int ln = lane & 15, quad = lane >> 4;
  const int w0 = wave >> 1, w1 = wave & 1;

  *(float4*)&invl[tid * 4] = *(const float4*)(inv + (size_t)b * 1024 + tid * 4);

  const bf16* qtile = Qb + ((size_t)b * 8 + (qt >> 1)) * 16384;
  const int qrow = (qt & 1) * 64 + w1 * 32 + ln;
  bf16x8 bq_[2][4];                             // [j: q 16-group][kk: d-granule4]
  for (int j = 0; j < 2; ++j)
    for (int kk = 0; kk < 4; ++kk)
      bq_[j][kk] = *(const bf16x8*)(qtile + (kk * 4 + quad) * 1024 + (qrow + j * 16) * 8);

  f32x4 oacc[2][4] = {};
  __syncthreads();                              // invl ready

  for (int kt2 = 0; kt2 < 16; ++kt2) {
    const bf16* ktile = Kb + ((size_t)b * 8 + (kt2 >> 1)) * 16384;
    const int krow = (kt2 & 1) * 64 + w0 * 32 + ln;

    // S^T: A = K-frag (m=k), B = Q-frag (n=q). 16 MFMA.
    f32x4 sacc[2][2] = {};
    for (int kk = 0; kk < 4; ++kk) {
      bf16x8 a0 = *(const bf16x8*)(ktile + (kk * 4 + quad) * 1024 + krow * 8);
      bf16x8 a1 = *(const bf16x8*)(ktile + (kk * 4 + quad) * 1024 + (krow + 16) * 8);
      sacc[0][0] = mfma16(a0, bq_[0][kk], sacc[0][0]);
      sacc[0][1] = mfma16(a0, bq_[1][kk], sacc[0][1]);
      sacc[1][0] = mfma16(a1, bq_[0][kk], sacc[1][0]);
      sacc[1][1] = mfma16(a1, bq_[1][kk], sacc[1][1]);
    }
    __syncthreads();                            // prev PV done reading Pl
    // p = exp2(s*C1) * inv[k]; C-frag regs are 4 consecutive k -> bf16x4 store
    for (int i = 0; i < 2; ++i) {
      int k_lo = w0 * 32 + i * 16 + quad * 4;   // local k (0..63)
      float4 iv = *(float4*)&invl[kt2 * 64 + k_lo];
      int kg = k_lo >> 3, koff = k_lo & 7;
      for (int j = 0; j < 2; ++j) {
        int qq = w1 * 32 + j * 16 + ln;
        bf16x4 pv = { (bf16)(fexp2(sacc[i][j][0] * EXP_C1) * iv.x),
                      (bf16)(fexp2(sacc[i][j][1] * EXP_C1) * iv.y),
                      (bf16)(fexp2(sacc[i][j][2] * EXP_C1) * iv.z),
                      (bf16)(fexp2(sacc[i][j][3] * EXP_C1) * iv.w) };
        *(bf16x4*)&Pl[kg * 512 + qq * 8 + koff] = pv;
      }
    }
    __syncthreads();                            // Pl complete
    // O += P @ Vc : A = P-frag (m=q) from LDS, B = V-frag (n=d) from global.
    const bf16* vt = VT + ((size_t)b * 8 + (kt2 >> 1)) * 16384;
    for (int ks = 0; ks < 64; ks += 32) {
      int kg = (ks >> 3) + quad;
      bf16x8 a0 = *(const bf16x8*)&Pl[kg * 512 + (w1 * 32 + ln) * 8];
      bf16x8 a1 = *(const bf16x8*)&Pl[kg * 512 + (w1 * 32 + 16 + ln) * 8];
      int s_local = (kt2 & 1) * 64 + ks + quad * 8;
      for (int j = 0; j < 4; ++j) {
        bf16x8 bv_ = *(const bf16x8*)(vt + (s_local >> 3) * 1024 + (w0 * 64 + j * 16 + ln) * 8);
        oacc[0][j] = mfma16(a0, bv_, oacc[0][j]);
        oacc[1][j] = mfma16(a1, bv_, oacc[1][j]);
      }
    }
  }

  // max over this block's 64 q rows, per output column d
  for (int j = 0; j < 4; ++j) {
    float m = -3.4e38f;
    for (int i = 0; i < 2; ++i)
      for (int rr = 0; rr < 4; ++rr)
        m = fmaxf(m, oacc[i][j][rr]);
    m = fmaxf(m, __shfl_xor(m, 16, 64));
    m = fmaxf(m, __shfl_xor(m, 32, 64));
    if (lane < 16) redm[w1 * 128 + w0 * 64 + j * 16 + lane] = m;
  }
  __syncthreads();
  if (tid < 128)
    Opart[((size_t)b * 16 + qt) * 128 + tid] = fmaxf(redm[tid], redm[128 + tid]);
}

// ============================================================================
// Kernel 4: final 16-way max over q-tiles -> d_out [64,128] fp32
// ============================================================================
__global__ __launch_bounds__(256) void k_final(
    const float* __restrict__ Opart, float* __restrict__ out)
{
  int t = blockIdx.x * 256 + threadIdx.x;       // 8192 outputs
  int b = t >> 7, d = t & 127;
  const float* p = Opart + (size_t)b * 2048 + d;
  float m = p[0];
  for (int i = 1; i < 16; ++i) m = fmaxf(m, p[(size_t)i * 128]);
  out[t] = m;
}

// ============================================================================
extern "C" void kernel_launch(void* const* d_in, const int* in_sizes, int n_in,
                              void* d_out, int out_size, void* d_ws, size_t ws_size,
                              hipStream_t stream) {
  const float* q  = (const float*)d_in[0];
  const float* Wq = (const float*)d_in[1];
  const float* bq = (const float*)d_in[2];
  const float* Wk = (const float*)d_in[3];
  const float* bk = (const float*)d_in[4];
  const float* Wv = (const float*)d_in[5];
  const float* bv = (const float*)d_in[6];
  float* out = (float*)d_out;

  char* ws = (char*)d_ws;
  bf16*  Qb    = (bf16*)(ws);                         // 16 MB granule tiles [s][d]
  bf16*  Kb    = (bf16*)(ws + (16u << 20));           // 16 MB
  bf16*  VT    = (bf16*)(ws + (32u << 20));           // 16 MB (V^T tiles [d][s])
  float* Opart = (float*)(ws + (48u << 20));          // 512 KB [64][16][128]
  float* inv   = (float*)(ws + (48u << 20) + (512u << 10)); // 256 KB [64][1024]
  bf16*  Wc    = (bf16*)(ws + (49u << 20));           // 192 KB [3][32][128][8]

  k_prep <<<48,           256, 0, stream>>>(Wq, Wk, Wv, Wc);
  k_qkv  <<<dim3(3, 512), 256, 0, stream>>>(q, Wc, bq, bk, bv, Qb, Kb, VT);
  k_stats<<<dim3(16, 64), 256, 0, stream>>>(Qb, Kb, inv);
  k_attn <<<dim3(16, 64), 256, 0, stream>>>(Qb, Kb, VT, inv, Opart);
  k_final<<<32, 256, 0, stream>>>(Opart, out);
}

// Round 5
// 191.173 us; speedup vs baseline: 1.3836x; 1.3836x over previous
//
#include <hip/hip_runtime.h>

// ---- types -----------------------------------------------------------------
typedef __bf16 bf16;
typedef __attribute__((ext_vector_type(8))) __bf16 bf16x8;
typedef __attribute__((ext_vector_type(4))) __bf16 bf16x4;
typedef __attribute__((ext_vector_type(4))) float  f32x4;

static __device__ __forceinline__ f32x4 mfma16(bf16x8 a, bf16x8 b, f32x4 c) {
  return __builtin_amdgcn_mfma_f32_16x16x32_bf16(a, b, c, 0, 0, 0);
}
static __device__ __forceinline__ float fexp2(float x) {
  return __builtin_amdgcn_exp2f(x);
}

// exp(s/sqrt(128)) = exp2(s * C1)
#define EXP_C1 (1.4426950408889634f / 11.313708498984760f)

// async global->LDS, 16B/lane; dst base is wave-uniform, HW adds lane*16.
typedef const __attribute__((address_space(1))) unsigned int gas_u32;
typedef __attribute__((address_space(3))) unsigned int las_u32;
#define GLDS16(gp, lp) __builtin_amdgcn_global_load_lds((gas_u32*)(gp), (las_u32*)(lp), 16, 0, 0)

// RACE FIX (round 4 -> 5): cross-wave DMA completion requires each wave to
// drain ITS OWN vmcnt BEFORE s_barrier. With the prefetch shape (DMA issued
// after barrier, consumed after the NEXT barrier) the compiler may place the
// vmcnt wait after the barrier (per-wave sound, cross-wave broken) -> stale
// LDS reads, rare + timing dependent. Pin the drain explicitly:
#define DMA_FENCE() __asm__ volatile("s_waitcnt vmcnt(0)" ::: "memory")

// Granule-major tile (128 rows x 128 cols bf16, 32KB): elem(r,c) = (c>>3)*1024 + r*8 + (c&7).
// MFMA fragments (16 rows x 8 cols) = contiguous 16B at 16B row stride.
// V is additionally ROW-PERMUTED (see k_qkv epilogue) so the PV MFMA can consume
// the QK^T C-fragment directly from registers: contraction slot (quad,e) of
// 32-block s holds V row k = 32s + quad*4 + (e&3) + 16*(e>>2).

// ============================================================================
// Kernel 0: prep. W[3][128][256] fp32 -> Wc[3][32 g][128 n][8] bf16.
// ============================================================================
__global__ __launch_bounds__(256) void k_prep(
    const float* __restrict__ Wq, const float* __restrict__ Wk,
    const float* __restrict__ Wv, bf16* __restrict__ Wc)
{
  int id = blockIdx.x * 256 + threadIdx.x;      // 48 blocks = 3*4096
  int proj = id >> 12, r = id & 4095;
  int g = r >> 7, n = r & 127;
  const float* W = proj == 0 ? Wq : proj == 1 ? Wk : Wv;
  const float4* src = (const float4*)(W + n * 256 + g * 8);
  float4 a = src[0], b = src[1];
  bf16x8 o = { (bf16)a.x, (bf16)a.y, (bf16)a.z, (bf16)a.w,
               (bf16)b.x, (bf16)b.y, (bf16)b.z, (bf16)b.w };
  *(bf16x8*)(Wc + (size_t)proj * 32768 + g * 1024 + n * 8) = o;
}

// ============================================================================
// Kernel 1: QKV projection. grid(512), block 256, 2 blocks/CU.
// Stage 128x256 q-slice ONCE in LDS (bank-padded chunks), one barrier, then
// 3 projection GEMMs (W from L2 as bf16 fragments). V written row-permuted.
// ============================================================================
__global__ __launch_bounds__(256, 2) void k_qkv(
    const float* __restrict__ q, const bf16* __restrict__ Wc,
    const float* __restrict__ bq, const float* __restrict__ bk, const float* __restrict__ bv,
    bf16* __restrict__ Qb, bf16* __restrict__ Kb, bf16* __restrict__ VT)
{
  __shared__ bf16 Al[32 * 1032];   // 32 x-granule chunks, stride 1032 elems (2064B, pads banks)

  const int tid = threadIdx.x, lane = tid & 63, wave = tid >> 6;
  const int ln = lane & 15, quad = lane >> 4;
  const int wr = wave >> 1, wc = wave & 1;      // 2x2 waves, 64x64 each
  const int m0 = blockIdx.x * 128;

  { // stage A: coalesced float4 (one row per wave per iter) -> bf16 chunks
    const float* src = q + (size_t)m0 * 256;
    for (int it = 0; it < 32; ++it) {
      int f = it * 1024 + tid * 4;
      int r = f >> 8, c = f & 255;
      float4 v = *(const float4*)(src + f);
      bf16x4 o = { (bf16)v.x, (bf16)v.y, (bf16)v.z, (bf16)v.w };
      *(bf16x4*)&Al[(c >> 3) * 1032 + r * 8 + (c & 7)] = o;
    }
  }
  __syncthreads();

  const int b = m0 >> 10, st = (m0 & 1023) >> 7;
  const size_t tbase = ((size_t)b * 8 + st) * 16384;

  for (int p = 0; p < 3; ++p) {
    const bf16* W = Wc + (size_t)p * 32768;
    const float* bias = p == 0 ? bq : p == 1 ? bk : bv;
    f32x4 acc[4][4] = {};
    for (int kk = 0; kk < 8; ++kk) {
      int g = kk * 4 + quad;
      bf16x8 af[4], bw[4];
      for (int i = 0; i < 4; ++i)
        af[i] = *(const bf16x8*)&Al[g * 1032 + (wr * 64 + i * 16 + ln) * 8];
      for (int j = 0; j < 4; ++j)
        bw[j] = *(const bf16x8*)(W + g * 1024 + (wc * 64 + j * 16 + ln) * 8);
      for (int i = 0; i < 4; ++i)
        for (int j = 0; j < 4; ++j)
          acc[i][j] = mfma16(af[i], bw[j], acc[i][j]);
    }

    if (p < 2) {                                // Q,K: granule-major [s][d]
      bf16* dst = (p == 0 ? Qb : Kb) + tbase;
      for (int j = 0; j < 4; ++j) {
        int d = wc * 64 + j * 16 + ln;
        float bb = bias[d];
        size_t gcol = (size_t)(d >> 3) * 1024 + (d & 7);
        for (int i = 0; i < 4; ++i) {
          int rbase = wr * 64 + i * 16 + quad * 4;
          for (int rr = 0; rr < 4; ++rr)
            dst[gcol + (size_t)(rbase + rr) * 8] = (bf16)(acc[i][j][rr] + bb);
        }
      }
    } else {                                    // V: [s-granule][d][8], ROW-PERMUTED
      bf16* dst = VT + tbase;
      for (int j = 0; j < 4; ++j) {
        int d = wc * 64 + j * 16 + ln;
        float bb = bias[d];
        for (int i = 0; i < 4; ++i) {
          int s0 = wr * 64 + i * 16 + quad * 4;               // 4 consecutive s
          int G  = (s0 >> 5) * 4 + ((s0 & 15) >> 2);          // permuted granule
          int e0 = (s0 & 16) >> 2;                            // 0 or 4
          bf16x4 o = { (bf16)(acc[i][j][0] + bb), (bf16)(acc[i][j][1] + bb),
                       (bf16)(acc[i][j][2] + bb), (bf16)(acc[i][j][3] + bb) };
          *(bf16x4*)&dst[(size_t)G * 1024 + (size_t)d * 8 + e0] = o;
        }
      }
    }
  }
}

// ============================================================================
// Kernel 2: column stats. grid(8 kt, 64 b), block 256, 2 blocks/CU.
// K-fragments REGISTER-resident (wave owns 32 k-rows); Q streamed via
// double-buffered global_load_lds, ONE barrier/iter (+ explicit DMA fence).
// ============================================================================
__global__ __launch_bounds__(256, 2) void k_stats(
    const bf16* __restrict__ Qb, const bf16* __restrict__ Kb, float* __restrict__ inv)
{
  __shared__ char Qbuf[2][32768];
  const int kt = blockIdx.x, b = blockIdx.y;
  const int tid = threadIdx.x, lane = tid & 63, wave = tid >> 6;
  const int ln = lane & 15, quad = lane >> 4;

  const bf16* ktile = Kb + ((size_t)b * 8 + kt) * 16384;
  bf16x8 ak[2][4];                              // wave's 32 k-rows, full d=128
  for (int i = 0; i < 2; ++i)
    for (int kk = 0; kk < 4; ++kk)
      ak[i][kk] = *(const bf16x8*)(ktile + (kk * 4 + quad) * 1024 + (wave * 32 + i * 16 + ln) * 8);

  const char* qb_b = (const char*)(Qb + (size_t)b * 8 * 16384);
  for (int c = 0; c < 8; ++c)                   // prologue DMA q-tile 0
    GLDS16(qb_b + (wave * 8 + c) * 1024 + lane * 16, &Qbuf[0][(wave * 8 + c) * 1024]);

  f32x4 csum[2] = {};
  for (int qt = 0; qt < 8; ++qt) {
    DMA_FENCE();                                // own DMA drained BEFORE barrier
    __syncthreads();                            // => all waves' DMA(qt) complete
    if (qt < 7)
      for (int c = 0; c < 8; ++c)
        GLDS16(qb_b + (size_t)(qt + 1) * 32768 + (wave * 8 + c) * 1024 + lane * 16,
               &Qbuf[(qt + 1) & 1][(wave * 8 + c) * 1024]);
    const char* Ql = Qbuf[qt & 1];
    for (int jq = 0; jq < 8; ++jq) {
      f32x4 s0 = {}, s1 = {};
      for (int kk = 0; kk < 4; ++kk) {
        bf16x8 bqf = *(const bf16x8*)(Ql + ((kk * 4 + quad) * 2 + (jq >> 2)) * 1024
                                         + ((jq * 16 + ln) & 63) * 16);
        s0 = mfma16(ak[0][kk], bqf, s0);
        s1 = mfma16(ak[1][kk], bqf, s1);
      }
      for (int rr = 0; rr < 4; ++rr) {
        csum[0][rr] += fexp2(s0[rr] * EXP_C1);
        csum[1][rr] += fexp2(s1[rr] * EXP_C1);
      }
    }
  }
  for (int i = 0; i < 2; ++i)
    for (int rr = 0; rr < 4; ++rr) {
      float v = csum[i][rr];
      v += __shfl_xor(v, 1, 64); v += __shfl_xor(v, 2, 64);
      v += __shfl_xor(v, 4, 64); v += __shfl_xor(v, 8, 64);
      csum[i][rr] = v;
    }
  if (ln == 0) {
    float* dst = inv + (size_t)b * 1024 + kt * 128 + wave * 32 + quad * 4;
    for (int i = 0; i < 2; ++i)
      for (int rr = 0; rr < 4; ++rr)
        dst[i * 16 + rr] = 1.0f / csum[i][rr];
  }
}

// ============================================================================
// Kernel 3: fused S^T=K Q^T -> P=exp*inv (IN REGISTERS) -> O += P Vc -> q-max.
// grid(8 qt, 64 b), block 256 (4 waves x 32q, each wave full 64k), 2 blocks/CU.
// Double-buffered K/V DMA, ONE barrier per k-tile (+ explicit DMA fence),
// 64 MFMA/wave between barriers. P repack uses the permuted-V contraction
// order (no LDS round-trip for P, no shfl).
// ============================================================================
__global__ __launch_bounds__(256, 2) void k_attn(
    const bf16* __restrict__ Qb, const bf16* __restrict__ Kb, const bf16* __restrict__ VT,
    const float* __restrict__ inv, float* __restrict__ Opart)
{
  __shared__ char buf[2][32768];                // [0,16K)=K chunks, [16K,32K)=V chunks
  __shared__ float invl[1024];
  __shared__ float redm[4][128];

  const int qt = blockIdx.x, b = blockIdx.y;
  const int tid = threadIdx.x, lane = tid & 63, wave = tid >> 6;
  const int ln = lane & 15, quad = lane >> 4;

  *(float4*)&invl[tid * 4] = *(const float4*)(inv + (size_t)b * 1024 + tid * 4);

  const bf16* qtile = Qb + ((size_t)b * 8 + qt) * 16384;
  bf16x8 bq_[2][4];                             // wave's 32 q-rows, full d
  for (int j = 0; j < 2; ++j)
    for (int kk = 0; kk < 4; ++kk)
      bq_[j][kk] = *(const bf16x8*)(qtile + (kk * 4 + quad) * 1024 + (wave * 32 + j * 16 + ln) * 8);

  const char* kb_b = (const char*)(Kb + (size_t)b * 8 * 16384);
  const char* vt_b = (const char*)(VT + (size_t)b * 8 * 16384);

#define DMA_TILE(t) do {                                                         \
    const char* ksrc = kb_b + (size_t)((t) >> 1) * 32768 + ((t) & 1) * 1024;     \
    const char* vsrc = vt_b + (size_t)((t) >> 1) * 32768 + ((t) & 1) * 16384;    \
    char* d_ = buf[(t) & 1];                                                     \
    for (int c = 0; c < 4; ++c) {                                                \
      int ch = wave * 4 + c;                                                     \
      GLDS16(ksrc + ch * 2048 + lane * 16, d_ + ch * 1024);                      \
      GLDS16(vsrc + (ch >> 1) * 2048 + (ch & 1) * 1024 + lane * 16,              \
             d_ + 16384 + ch * 1024);                                            \
    }                                                                            \
  } while (0)

  f32x4 oacc[2][8] = {};
  DMA_TILE(0);

  for (int t = 0; t < 16; ++t) {
    DMA_FENCE();                                // own DMA drained BEFORE barrier
    __syncthreads();                            // => all waves' DMA(t) complete
    if (t < 15) DMA_TILE(t + 1);
    const char* Kl = buf[t & 1];
    const char* Vl = buf[t & 1] + 16384;

    // S^T = K Q^T : wave covers all 64 k x its 32 q. 32 MFMA.
    f32x4 sacc[4][2] = {};
    for (int kk = 0; kk < 4; ++kk) {
      bf16x8 ak[4];
      for (int i = 0; i < 4; ++i)
        ak[i] = *(const bf16x8*)(Kl + (kk * 4 + quad) * 1024 + (i * 16 + ln) * 16);
      for (int i = 0; i < 4; ++i)
        for (int j = 0; j < 2; ++j)
          sacc[i][j] = mfma16(ak[i], bq_[j][kk], sacc[i][j]);
    }
    // P = exp2(S*C1)*inv[k], repacked in registers into PV A-fragments.
    // pf element e of step s carries k = 32s + quad*4 + (e&3) + 16*(e>>2),
    // matching the permuted V rows.
    bf16x8 pf[2][2];
    for (int s = 0; s < 2; ++s) {
      float4 iv0 = *(float4*)&invl[t * 64 + (2 * s) * 16 + quad * 4];
      float4 iv1 = *(float4*)&invl[t * 64 + (2 * s + 1) * 16 + quad * 4];
      for (int j = 0; j < 2; ++j) {
        f32x4 lo = sacc[2 * s][j], hi = sacc[2 * s + 1][j];
        pf[j][s] = bf16x8{
          (bf16)(fexp2(lo[0] * EXP_C1) * iv0.x), (bf16)(fexp2(lo[1] * EXP_C1) * iv0.y),
          (bf16)(fexp2(lo[2] * EXP_C1) * iv0.z), (bf16)(fexp2(lo[3] * EXP_C1) * iv0.w),
          (bf16)(fexp2(hi[0] * EXP_C1) * iv1.x), (bf16)(fexp2(hi[1] * EXP_C1) * iv1.y),
          (bf16)(fexp2(hi[2] * EXP_C1) * iv1.z), (bf16)(fexp2(hi[3] * EXP_C1) * iv1.w) };
      }
    }
    // O += P @ Vc : 32 MFMA, B-frags from permuted Vl.
    for (int s = 0; s < 2; ++s)
      for (int j2 = 0; j2 < 8; ++j2) {
        bf16x8 bv_ = *(const bf16x8*)(Vl + ((s * 4 + quad) * 2 + (j2 >> 2)) * 1024
                                         + ((j2 * 16 + ln) & 63) * 16);
        oacc[0][j2] = mfma16(pf[0][s], bv_, oacc[0][j2]);
        oacc[1][j2] = mfma16(pf[1][s], bv_, oacc[1][j2]);
      }
  }

  // max over this block's 128 q rows, per output column d
  for (int j2 = 0; j2 < 8; ++j2) {
    float m = -3.4e38f;
    for (int j = 0; j < 2; ++j)
      for (int rr = 0; rr < 4; ++rr)
        m = fmaxf(m, oacc[j][j2][rr]);
    m = fmaxf(m, __shfl_xor(m, 16, 64));
    m = fmaxf(m, __shfl_xor(m, 32, 64));
    if (lane < 16) redm[wave][j2 * 16 + ln] = m;
  }
  __syncthreads();
  if (tid < 128)
    Opart[((size_t)b * 8 + qt) * 128 + tid] =
      fmaxf(fmaxf(redm[0][tid], redm[1][tid]), fmaxf(redm[2][tid], redm[3][tid]));
}

// ============================================================================
// Kernel 4: final 8-way max over q-tiles -> d_out [64,128] fp32
// ============================================================================
__global__ __launch_bounds__(256) void k_final(
    const float* __restrict__ Opart, float* __restrict__ out)
{
  int t = blockIdx.x * 256 + threadIdx.x;       // 8192 outputs
  int b = t >> 7, d = t & 127;
  const float* p = Opart + (size_t)b * 1024 + d;
  float m = p[0];
  for (int i = 1; i < 8; ++i) m = fmaxf(m, p[(size_t)i * 128]);
  out[t] = m;
}

// ============================================================================
extern "C" void kernel_launch(void* const* d_in, const int* in_sizes, int n_in,
                              void* d_out, int out_size, void* d_ws, size_t ws_size,
                              hipStream_t stream) {
  const float* q  = (const float*)d_in[0];
  const float* Wq = (const float*)d_in[1];
  const float* bq = (const float*)d_in[2];
  const float* Wk = (const float*)d_in[3];
  const float* bk = (const float*)d_in[4];
  const float* Wv = (const float*)d_in[5];
  const float* bv = (const float*)d_in[6];
  float* out = (float*)d_out;

  char* ws = (char*)d_ws;
  bf16*  Qb    = (bf16*)(ws);                         // 16 MB granule tiles [s][d]
  bf16*  Kb    = (bf16*)(ws + (16u << 20));           // 16 MB
  bf16*  VT    = (bf16*)(ws + (32u << 20));           // 16 MB (V^T, row-permuted)
  float* inv   = (float*)(ws + (48u << 20));          // 256 KB [64][1024]
  float* Opart = (float*)(ws + (48u << 20) + (512u << 10)); // 256 KB [64][8][128]
  bf16*  Wc    = (bf16*)(ws + (49u << 20));           // 192 KB [3][32][128][8]

  k_prep <<<48,           256, 0, stream>>>(Wq, Wk, Wv, Wc);
  k_qkv  <<<dim3(512),    256, 0, stream>>>(q, Wc, bq, bk, bv, Qb, Kb, VT);
  k_stats<<<dim3(8, 64),  256, 0, stream>>>(Qb, Kb, inv);
  k_attn <<<dim3(8, 64),  256, 0, stream>>>(Qb, Kb, VT, inv, Opart);
  k_final<<<32, 256, 0, stream>>>(Opart, out);
}

// Round 6
// 184.044 us; speedup vs baseline: 1.4372x; 1.0387x over previous
//
#include <hip/hip_runtime.h>

// ---- types -----------------------------------------------------------------
typedef __bf16 bf16;
typedef __attribute__((ext_vector_type(8))) __bf16 bf16x8;
typedef __attribute__((ext_vector_type(4))) __bf16 bf16x4;
typedef __attribute__((ext_vector_type(4))) float  f32x4;

static __device__ __forceinline__ f32x4 mfma16(bf16x8 a, bf16x8 b, f32x4 c) {
  return __builtin_amdgcn_mfma_f32_16x16x32_bf16(a, b, c, 0, 0, 0);
}
static __device__ __forceinline__ float fexp2(float x) {
  return __builtin_amdgcn_exp2f(x);
}

// exp(s/sqrt(128)) = exp2(s * C1)
#define EXP_C1 (1.4426950408889634f / 11.313708498984760f)

// async global->LDS, 16B/lane; dst base is wave-uniform, HW adds lane*16.
typedef const __attribute__((address_space(1))) unsigned int gas_u32;
typedef __attribute__((address_space(3))) unsigned int las_u32;
#define GLDS16(gp, lp) __builtin_amdgcn_global_load_lds((gas_u32*)(gp), (las_u32*)(lp), 16, 0, 0)

// RACE FIX (r4->r5, keep): drain own vmcnt BEFORE s_barrier so cross-wave
// DMA completion is guaranteed (compiler would otherwise defer the wait).
#define DMA_FENCE() __asm__ volatile("s_waitcnt vmcnt(0)" ::: "memory")

// Granule-major tile (128 rows x 128 cols bf16, 32KB): elem(r,c) = (c>>3)*1024 + r*8 + (c&7).
// MFMA fragments (16 rows x 8 cols) = contiguous 16B at 16B row stride.
// V is ROW-PERMUTED (k_qkv epilogue) so the PV MFMA consumes the QK^T
// C-fragment from registers: slot (quad,e) of 32-block s holds V row
// k = 32s + quad*4 + (e&3) + 16*(e>>2).
//
// XCD SWIZZLE (r5->r6): grids are (64 b, T tiles) with b on X. Same-b blocks
// have linear ids stride 64 (== 0 mod 8 XCDs) -> same XCD -> K/V/Q of a batch
// stay in that XCD's 4MB L2 across its 8 tile-blocks.

// ============================================================================
// Kernel 0: prep. W[3][128][256] fp32 -> Wc[3][32 g][128 n][8] bf16.
// ============================================================================
__global__ __launch_bounds__(256) void k_prep(
    const float* __restrict__ Wq, const float* __restrict__ Wk,
    const float* __restrict__ Wv, bf16* __restrict__ Wc)
{
  int id = blockIdx.x * 256 + threadIdx.x;      // 48 blocks = 3*4096
  int proj = id >> 12, r = id & 4095;
  int g = r >> 7, n = r & 127;
  const float* W = proj == 0 ? Wq : proj == 1 ? Wk : Wv;
  const float4* src = (const float4*)(W + n * 256 + g * 8);
  float4 a = src[0], b = src[1];
  bf16x8 o = { (bf16)a.x, (bf16)a.y, (bf16)a.z, (bf16)a.w,
               (bf16)b.x, (bf16)b.y, (bf16)b.z, (bf16)b.w };
  *(bf16x8*)(Wc + (size_t)proj * 32768 + g * 1024 + n * 8) = o;
}

// ============================================================================
// Kernel 1: QKV projection. grid(512), block 256, 2 blocks/CU.
// Stage 128x256 q-slice once in LDS, one barrier, 3 projection GEMMs.
// Q/K use SWAPPED MFMA operands (A=W => C-regs = 4 consecutive d) so the
// epilogue is 16 packed bf16x4 stores (was 64 scalar). V unchanged (already
// packed via its row permutation).
// ============================================================================
__global__ __launch_bounds__(256, 2) void k_qkv(
    const float* __restrict__ q, const bf16* __restrict__ Wc,
    const float* __restrict__ bq, const float* __restrict__ bk, const float* __restrict__ bv,
    bf16* __restrict__ Qb, bf16* __restrict__ Kb, bf16* __restrict__ VT)
{
  __shared__ bf16 Al[32 * 1032];   // 32 x-granule chunks, stride 1032 elems

  const int tid = threadIdx.x, lane = tid & 63, wave = tid >> 6;
  const int ln = lane & 15, quad = lane >> 4;
  const int wr = wave >> 1, wc = wave & 1;      // 2x2 waves, 64x64 each
  const int m0 = blockIdx.x * 128;

  { // stage A: coalesced float4 -> bf16 chunks
    const float* src = q + (size_t)m0 * 256;
    for (int it = 0; it < 32; ++it) {
      int f = it * 1024 + tid * 4;
      int r = f >> 8, c = f & 255;
      float4 v = *(const float4*)(src + f);
      bf16x4 o = { (bf16)v.x, (bf16)v.y, (bf16)v.z, (bf16)v.w };
      *(bf16x4*)&Al[(c >> 3) * 1032 + r * 8 + (c & 7)] = o;
    }
  }
  __syncthreads();

  const int b = m0 >> 10, st = (m0 & 1023) >> 7;
  const size_t tbase = ((size_t)b * 8 + st) * 16384;

  for (int p = 0; p < 3; ++p) {
    const bf16* W = Wc + (size_t)p * 32768;
    const float* bias = p == 0 ? bq : p == 1 ? bk : bv;
    f32x4 acc[4][4] = {};
    for (int kk = 0; kk < 8; ++kk) {
      int g = kk * 4 + quad;
      bf16x8 ax[4], bw[4];
      for (int t = 0; t < 4; ++t)
        ax[t] = *(const bf16x8*)&Al[g * 1032 + (wr * 64 + t * 16 + ln) * 8];
      for (int t = 0; t < 4; ++t)
        bw[t] = *(const bf16x8*)(W + g * 1024 + (wc * 64 + t * 16 + ln) * 8);
      if (p < 2) {
        for (int i = 0; i < 4; ++i)               // D[d][s]: A=W (m=d), B=X (n=s)
          for (int j = 0; j < 4; ++j)
            acc[i][j] = mfma16(bw[i], ax[j], acc[i][j]);
      } else {
        for (int i = 0; i < 4; ++i)               // D[s][d]: A=X (m=s), B=W (n=d)
          for (int j = 0; j < 4; ++j)
            acc[i][j] = mfma16(ax[i], bw[j], acc[i][j]);
      }
    }

    if (p < 2) {   // Q,K granule-major [s][d]; regs = 4 consecutive d -> bf16x4
      bf16* dst = (p == 0 ? Qb : Kb) + tbase;
      for (int i = 0; i < 4; ++i) {
        float4 b4 = *(const float4*)&bias[wc * 64 + i * 16 + quad * 4];
        int gd = wc * 8 + i * 2 + (quad >> 1);    // d-granule
        int e0 = (quad & 1) * 4;
        for (int j = 0; j < 4; ++j) {
          int s = wr * 64 + j * 16 + ln;
          bf16x4 o = { (bf16)(acc[i][j][0] + b4.x), (bf16)(acc[i][j][1] + b4.y),
                       (bf16)(acc[i][j][2] + b4.z), (bf16)(acc[i][j][3] + b4.w) };
          *(bf16x4*)&dst[(size_t)gd * 1024 + (size_t)s * 8 + e0] = o;
        }
      }
    } else {       // V: [s-granule][d][8], ROW-PERMUTED
      bf16* dst = VT + tbase;
      for (int j = 0; j < 4; ++j) {
        int d = wc * 64 + j * 16 + ln;
        float bb = bias[d];
        for (int i = 0; i < 4; ++i) {
          int s0 = wr * 64 + i * 16 + quad * 4;
          int G  = (s0 >> 5) * 4 + ((s0 & 15) >> 2);
          int e0 = (s0 & 16) >> 2;
          bf16x4 o = { (bf16)(acc[i][j][0] + bb), (bf16)(acc[i][j][1] + bb),
                       (bf16)(acc[i][j][2] + bb), (bf16)(acc[i][j][3] + bb) };
          *(bf16x4*)&dst[(size_t)G * 1024 + (size_t)d * 8 + e0] = o;
        }
      }
    }
  }
}

// ============================================================================
// Kernel 2: column stats. grid(64 b, 8 kt) [XCD-swizzled], block 256.
// K-fragments register-resident; Q streamed via double-buffered DMA.
// ============================================================================
__global__ __launch_bounds__(256, 2) void k_stats(
    const bf16* __restrict__ Qb, const bf16* __restrict__ Kb, float* __restrict__ inv)
{
  __shared__ char Qbuf[2][32768];
  const int b = blockIdx.x, kt = blockIdx.y;
  const int tid = threadIdx.x, lane = tid & 63, wave = tid >> 6;
  const int ln = lane & 15, quad = lane >> 4;

  const bf16* ktile = Kb + ((size_t)b * 8 + kt) * 16384;
  bf16x8 ak[2][4];                              // wave's 32 k-rows, full d=128
  for (int i = 0; i < 2; ++i)
    for (int kk = 0; kk < 4; ++kk)
      ak[i][kk] = *(const bf16x8*)(ktile + (kk * 4 + quad) * 1024 + (wave * 32 + i * 16 + ln) * 8);

  const char* qb_b = (const char*)(Qb + (size_t)b * 8 * 16384);
  for (int c = 0; c < 8; ++c)                   // prologue DMA q-tile 0
    GLDS16(qb_b + (wave * 8 + c) * 1024 + lane * 16, &Qbuf[0][(wave * 8 + c) * 1024]);

  f32x4 csum[2] = {};
  for (int qt = 0; qt < 8; ++qt) {
    DMA_FENCE();
    __syncthreads();                            // all waves' DMA(qt) complete
    if (qt < 7)
      for (int c = 0; c < 8; ++c)
        GLDS16(qb_b + (size_t)(qt + 1) * 32768 + (wave * 8 + c) * 1024 + lane * 16,
               &Qbuf[(qt + 1) & 1][(wave * 8 + c) * 1024]);
    const char* Ql = Qbuf[qt & 1];
    for (int jq = 0; jq < 8; ++jq) {
      f32x4 s0 = {}, s1 = {};
      for (int kk = 0; kk < 4; ++kk) {
        bf16x8 bqf = *(const bf16x8*)(Ql + ((kk * 4 + quad) * 2 + (jq >> 2)) * 1024
                                         + ((jq * 16 + ln) & 63) * 16);
        s0 = mfma16(ak[0][kk], bqf, s0);
        s1 = mfma16(ak[1][kk], bqf, s1);
      }
      for (int rr = 0; rr < 4; ++rr) {
        csum[0][rr] += fexp2(s0[rr] * EXP_C1);
        csum[1][rr] += fexp2(s1[rr] * EXP_C1);
      }
    }
  }
  for (int i = 0; i < 2; ++i)
    for (int rr = 0; rr < 4; ++rr) {
      float v = csum[i][rr];
      v += __shfl_xor(v, 1, 64); v += __shfl_xor(v, 2, 64);
      v += __shfl_xor(v, 4, 64); v += __shfl_xor(v, 8, 64);
      csum[i][rr] = v;
    }
  if (ln == 0) {
    float* dst = inv + (size_t)b * 1024 + kt * 128 + wave * 32 + quad * 4;
    for (int i = 0; i < 2; ++i)
      for (int rr = 0; rr < 4; ++rr)
        dst[i * 16 + rr] = 1.0f / csum[i][rr];
  }
}

// ============================================================================
// Kernel 3: fused S^T=K Q^T -> P=exp*inv (in regs) -> O += P Vc -> q-max.
// grid(64 b, 8 qt) [XCD-swizzled], block 256 (4 waves x 32q), 2 blocks/CU.
// Double-buffered K/V DMA, one barrier + fence per k-tile, 64 MFMA/wave.
// ============================================================================
__global__ __launch_bounds__(256, 2) void k_attn(
    const bf16* __restrict__ Qb, const bf16* __restrict__ Kb, const bf16* __restrict__ VT,
    const float* __restrict__ inv, float* __restrict__ Opart)
{
  __shared__ char buf[2][32768];                // [0,16K)=K chunks, [16K,32K)=V chunks
  __shared__ float invl[1024];
  __shared__ float redm[4][128];

  const int b = blockIdx.x, qt = blockIdx.y;
  const int tid = threadIdx.x, lane = tid & 63, wave = tid >> 6;
  const int ln = lane & 15, quad = lane >> 4;

  *(float4*)&invl[tid * 4] = *(const float4*)(inv + (size_t)b * 1024 + tid * 4);

  const bf16* qtile = Qb + ((size_t)b * 8 + qt) * 16384;
  bf16x8 bq_[2][4];                             // wave's 32 q-rows, full d
  for (int j = 0; j < 2; ++j)
    for (int kk = 0; kk < 4; ++kk)
      bq_[j][kk] = *(const bf16x8*)(qtile + (kk * 4 + quad) * 1024 + (wave * 32 + j * 16 + ln) * 8);

  const char* kb_b = (const char*)(Kb + (size_t)b * 8 * 16384);
  const char* vt_b = (const char*)(VT + (size_t)b * 8 * 16384);

#define DMA_TILE(t) do {                                                         \
    const char* ksrc = kb_b + (size_t)((t) >> 1) * 32768 + ((t) & 1) * 1024;     \
    const char* vsrc = vt_b + (size_t)((t) >> 1) * 32768 + ((t) & 1) * 16384;    \
    char* d_ = buf[(t) & 1];                                                     \
    for (int c = 0; c < 4; ++c) {                                                \
      int ch = wave * 4 + c;                                                     \
      GLDS16(ksrc + ch * 2048 + lane * 16, d_ + ch * 1024);                      \
      GLDS16(vsrc + (ch >> 1) * 2048 + (ch & 1) * 1024 + lane * 16,              \
             d_ + 16384 + ch * 1024);                                            \
    }                                                                            \
  } while (0)

  f32x4 oacc[2][8] = {};
  DMA_TILE(0);

  for (int t = 0; t < 16; ++t) {
    DMA_FENCE();
    __syncthreads();                            // all waves' DMA(t) complete
    if (t < 15) DMA_TILE(t + 1);
    const char* Kl = buf[t & 1];
    const char* Vl = buf[t & 1] + 16384;

    // S^T = K Q^T : wave covers all 64 k x its 32 q. 32 MFMA.
    f32x4 sacc[4][2] = {};
    for (int kk = 0; kk < 4; ++kk) {
      bf16x8 ak[4];
      for (int i = 0; i < 4; ++i)
        ak[i] = *(const bf16x8*)(Kl + (kk * 4 + quad) * 1024 + (i * 16 + ln) * 16);
      for (int i = 0; i < 4; ++i)
        for (int j = 0; j < 2; ++j)
          sacc[i][j] = mfma16(ak[i], bq_[j][kk], sacc[i][j]);
    }
    // P = exp2(S*C1)*inv[k], repacked in registers into PV A-fragments
    // (element e of step s carries k = 32s + quad*4 + (e&3) + 16*(e>>2)).
    bf16x8 pf[2][2];
    for (int s = 0; s < 2; ++s) {
      float4 iv0 = *(float4*)&invl[t * 64 + (2 * s) * 16 + quad * 4];
      float4 iv1 = *(float4*)&invl[t * 64 + (2 * s + 1) * 16 + quad * 4];
      for (int j = 0; j < 2; ++j) {
        f32x4 lo = sacc[2 * s][j], hi = sacc[2 * s + 1][j];
        pf[j][s] = bf16x8{
          (bf16)(fexp2(lo[0] * EXP_C1) * iv0.x), (bf16)(fexp2(lo[1] * EXP_C1) * iv0.y),
          (bf16)(fexp2(lo[2] * EXP_C1) * iv0.z), (bf16)(fexp2(lo[3] * EXP_C1) * iv0.w),
          (bf16)(fexp2(hi[0] * EXP_C1) * iv1.x), (bf16)(fexp2(hi[1] * EXP_C1) * iv1.y),
          (bf16)(fexp2(hi[2] * EXP_C1) * iv1.z), (bf16)(fexp2(hi[3] * EXP_C1) * iv1.w) };
      }
    }
    // O += P @ Vc : 32 MFMA, B-frags from permuted Vl.
    for (int s = 0; s < 2; ++s)
      for (int j2 = 0; j2 < 8; ++j2) {
        bf16x8 bv_ = *(const bf16x8*)(Vl + ((s * 4 + quad) * 2 + (j2 >> 2)) * 1024
                                         + ((j2 * 16 + ln) & 63) * 16);
        oacc[0][j2] = mfma16(pf[0][s], bv_, oacc[0][j2]);
        oacc[1][j2] = mfma16(pf[1][s], bv_, oacc[1][j2]);
      }
  }

  // max over this block's 128 q rows, per output column d
  for (int j2 = 0; j2 < 8; ++j2) {
    float m = -3.4e38f;
    for (int j = 0; j < 2; ++j)
      for (int rr = 0; rr < 4; ++rr)
        m = fmaxf(m, oacc[j][j2][rr]);
    m = fmaxf(m, __shfl_xor(m, 16, 64));
    m = fmaxf(m, __shfl_xor(m, 32, 64));
    if (lane < 16) redm[wave][j2 * 16 + ln] = m;
  }
  __syncthreads();
  if (tid < 128)
    Opart[((size_t)b * 8 + qt) * 128 + tid] =
      fmaxf(fmaxf(redm[0][tid], redm[1][tid]), fmaxf(redm[2][tid], redm[3][tid]));
}

// ============================================================================
// Kernel 4: final 8-way max over q-tiles -> d_out [64,128] fp32
// ============================================================================
__global__ __launch_bounds__(256) void k_final(
    const float* __restrict__ Opart, float* __restrict__ out)
{
  int t = blockIdx.x * 256 + threadIdx.x;       // 8192 outputs
  int b = t >> 7, d = t & 127;
  const float* p = Opart + (size_t)b * 1024 + d;
  float m = p[0];
  for (int i = 1; i < 8; ++i) m = fmaxf(m, p[(size_t)i * 128]);
  out[t] = m;
}

// ============================================================================
extern "C" void kernel_launch(void* const* d_in, const int* in_sizes, int n_in,
                              void* d_out, int out_size, void* d_ws, size_t ws_size,
                              hipStream_t stream) {
  const float* q  = (const float*)d_in[0];
  const float* Wq = (const float*)d_in[1];
  const float* bq = (const float*)d_in[2];
  const float* Wk = (const float*)d_in[3];
  const float* bk = (const float*)d_in[4];
  const float* Wv = (const float*)d_in[5];
  const float* bv = (const float*)d_in[6];
  float* out = (float*)d_out;

  char* ws = (char*)d_ws;
  bf16*  Qb    = (bf16*)(ws);                         // 16 MB granule tiles [s][d]
  bf16*  Kb    = (bf16*)(ws + (16u << 20));           // 16 MB
  bf16*  VT    = (bf16*)(ws + (32u << 20));           // 16 MB (V^T, row-permuted)
  float* inv   = (float*)(ws + (48u << 20));          // 256 KB [64][1024]
  float* Opart = (float*)(ws + (48u << 20) + (512u << 10)); // 256 KB [64][8][128]
  bf16*  Wc    = (bf16*)(ws + (49u << 20));           // 192 KB [3][32][128][8]

  k_prep <<<48,           256, 0, stream>>>(Wq, Wk, Wv, Wc);
  k_qkv  <<<dim3(512),    256, 0, stream>>>(q, Wc, bq, bk, bv, Qb, Kb, VT);
  k_stats<<<dim3(64, 8),  256, 0, stream>>>(Qb, Kb, inv);
  k_attn <<<dim3(64, 8),  256, 0, stream>>>(Qb, Kb, VT, inv, Opart);
  k_final<<<32, 256, 0, stream>>>(Opart, out);
}